// Round 3
// baseline (353.094 us; speedup 1.0000x reference)
//
#include <hip/hip_runtime.h>

typedef __attribute__((ext_vector_type(8))) short bf16x8;
typedef __attribute__((ext_vector_type(4))) float f32x4;

#define OUT0 524288           // B*G*E
#define SRC_CH_STRIDE 8388608 // B*G*G = 2*2048*2048
#define NSLICE 8              // p-slices (256 p each)
#define PART_HEAD 544         // m[16] + l[16] + O[16*32]
#define PART_SET 2176         // 4 heads * 544

__device__ __forceinline__ unsigned short f2bf(float x){
    unsigned u = __builtin_bit_cast(unsigned, x);
    u += 0x7FFFu + ((u >> 16) & 1u);
    return (unsigned short)(u >> 16);
}
__device__ __forceinline__ unsigned short bftrunc(float x){
    return (unsigned short)(__builtin_bit_cast(unsigned, x) >> 16);
}

// DPP row-rotate (16-lane rows == our quads); rotate-reduce is valid for max/sum.
template<int CTRL>
__device__ __forceinline__ float rr16(float x){
    int i = __builtin_bit_cast(int, x);
    i = __builtin_amdgcn_mov_dpp(i, CTRL, 0xf, 0xf, true);
    return __builtin_bit_cast(float, i);
}
__device__ __forceinline__ float redmax16(float v){
    v = fmaxf(v, rr16<0x128>(v));  // row_ror:8
    v = fmaxf(v, rr16<0x124>(v));  // row_ror:4
    v = fmaxf(v, rr16<0x122>(v));  // row_ror:2
    v = fmaxf(v, rr16<0x121>(v));  // row_ror:1
    return v;
}
__device__ __forceinline__ float redsum16(float v){
    v += rr16<0x128>(v);
    v += rr16<0x124>(v);
    v += rr16<0x122>(v);
    v += rr16<0x121>(v);
    return v;
}

// ---------------- kernel 1: QKV projection ----------------
// Q,K -> bf16 [b][g][head*32+k] ; V -> bf16 transposed [b][head*32+v][g]
__global__ __launch_bounds__(256) void qkv_kernel(
    const float* __restrict__ hsrc,
    const float* __restrict__ Wq, const float* __restrict__ Wk, const float* __restrict__ Wv,
    unsigned short* __restrict__ Qb, unsigned short* __restrict__ Kb, unsigned short* __restrict__ Vt)
{
    __shared__ float hs[32*128];
    __shared__ float ws[128*32];
    const int t = threadIdx.x;
    const int g0 = blockIdx.x * 32;
    const int mat = blockIdx.y;
    const int mt = mat >> 2, head = mat & 3;
    {
        const float4* s = (const float4*)(hsrc + g0*128);
        float4* d = (float4*)hs;
        #pragma unroll
        for (int i=0;i<4;i++) d[t + i*256] = s[t + i*256];
        const float* W = (mt==0?Wq:(mt==1?Wk:Wv)) + head*4096;
        const float4* s2 = (const float4*)W;
        float4* d2 = (float4*)ws;
        #pragma unroll
        for (int i=0;i<4;i++) d2[t + i*256] = s2[t + i*256];
    }
    __syncthreads();
    const int r = t >> 3;
    const int k0 = (t & 7) * 4;
    float a0=0.f,a1=0.f,a2=0.f,a3=0.f;
    const float* hr = hs + r*128;
    #pragma unroll 8
    for (int d=0; d<128; d++){
        float hv = hr[d];
        float4 w4 = *(const float4*)(ws + d*32 + k0);
        a0 = fmaf(hv, w4.x, a0); a1 = fmaf(hv, w4.y, a1);
        a2 = fmaf(hv, w4.z, a2); a3 = fmaf(hv, w4.w, a3);
    }
    const int row_g = g0 + r;
    if (mt == 2){
        const int b = row_g >> 11, g = row_g & 2047;
        unsigned short* dst = Vt + ((b*128 + head*32 + k0) * 2048) + g;
        dst[0] = f2bf(a0); dst[2048] = f2bf(a1); dst[4096] = f2bf(a2); dst[6144] = f2bf(a3);
    } else {
        unsigned short* dst = (mt==0?Qb:Kb) + row_g*128 + head*32 + k0;
        dst[0]=f2bf(a0); dst[1]=f2bf(a1); dst[2]=f2bf(a2); dst[3]=f2bf(a3);
    }
}

// ---------------- kernel 2: fused attention, wave-independent ----------------
// grid (32 q-quads, B=2, NSLICE), block 256 = 4 INDEPENDENT waves.
// Wave wv handles q-tile (blockIdx.x*4+wv), ALL 4 heads, 256-p slice.
// No __syncthreads in the main loop: P transpose goes through wave-private LDS.
__global__ __launch_bounds__(256,2) void attn_kernel(
    const float* __restrict__ src,
    const unsigned short* __restrict__ Qb,
    const unsigned short* __restrict__ Kb,
    const unsigned short* __restrict__ Vt,
    const float* __restrict__ w1g, const float* __restrict__ b1g,
    const float* __restrict__ w2g, const float* __restrict__ b2g,
    float* __restrict__ part)
{
    __shared__ __align__(16) unsigned short Pb_lds[16*16*72]; // [wv*4+h][16 q][72]
    __shared__ float wt[112];

    const int t = threadIdx.x;
    if (t < 64) wt[t] = w1g[t];
    else if (t < 72) wt[t] = b1g[t-64];
    else if (t < 104) wt[t] = w2g[t-72];
    else if (t < 108) wt[t] = b2g[t-104];
    __syncthreads();   // only barrier: weights ready

    const int lane = t & 63, wv = t >> 6;
    const int quad = lane >> 4, lrow = lane & 15;
    const int qt = blockIdx.x*4 + wv, q0 = qt*16;
    const int b = blockIdx.y, s = blockIdx.z;
    const int pbase = s * 256;

    // Q fragments (A-layout: m=lrow, k=quad*8+j), one per head
    bf16x8 qf[4];
    #pragma unroll
    for (int h=0;h<4;h++)
        qf[h] = *(const bf16x8*)(Qb + (b*2048 + q0 + lrow)*128 + h*32 + quad*8);

    f32x4 o[4][2];
    float m[4][4], l[4][4];
    #pragma unroll
    for (int h=0;h<4;h++){
        o[h][0] = (f32x4){0.f,0.f,0.f,0.f};
        o[h][1] = (f32x4){0.f,0.f,0.f,0.f};
        #pragma unroll
        for (int r=0;r<4;r++){ m[h][r] = -1e30f; l[h][r] = 0.f; }
    }
    const f32x4 zero4 = {0.f,0.f,0.f,0.f};

    float* dstbase = (float*)0;  // computed per use

    for (int rnd = 0; rnd < 8; rnd++){
        const int prnd = pbase + rnd*32;
        float z[2][4][4];   // [sub][out-ch][r]

        #pragma unroll
        for (int sub=0; sub<2; sub++){
            const int psub = prnd + sub*16;
            // scores: all 4 heads; C layout row(q)=quad*4+r, col(p)=lrow
            f32x4 sc[4];
            #pragma unroll
            for (int h=0;h<4;h++){
                const bf16x8 kf = *(const bf16x8*)(Kb + (b*2048 + psub + lrow)*128 + h*32 + quad*8);
                sc[h] = __builtin_amdgcn_mfma_f32_16x16x32_bf16(qf[h], kf, zero4, 0, 0, 0);
            }
            // src channels for this lane's 4 cells (+ write-through to out copy)
            float xsrc[4][4];
            #pragma unroll
            for (int ch=0; ch<4; ch++){
                const int off = ch*SRC_CH_STRIDE + (b*2048 + q0 + quad*4)*2048 + psub + lrow;
                const float* sp = src + off;
                float* op = part + 0;  // placeholder, real out ptr passed via part? no:
                (void)op;
                #pragma unroll
                for (int r=0;r<4;r++){ xsrc[ch][r] = sp[r*2048]; }
            }
            // per-cell MLP: channels 0-3 = scores, 4-7 = src
            float zz[4][4];
            #pragma unroll
            for (int cc=0;cc<4;cc++){
                float bb = wt[104+cc];
                #pragma unroll
                for (int r=0;r<4;r++) zz[cc][r] = bb;
            }
            #pragma unroll
            for (int j=0;j<8;j++){
                float w0=wt[j*8+0], w1v=wt[j*8+1], w2v=wt[j*8+2], w3=wt[j*8+3];
                float w4v=wt[j*8+4], w5=wt[j*8+5], w6=wt[j*8+6], w7=wt[j*8+7];
                float bj = wt[64+j];
                #pragma unroll
                for (int r=0;r<4;r++){
                    float v = bj;
                    v = fmaf(w0,  sc[0][r], v);
                    v = fmaf(w1v, sc[1][r], v);
                    v = fmaf(w2v, sc[2][r], v);
                    v = fmaf(w3,  sc[3][r], v);
                    v = fmaf(w4v, xsrc[0][r], v);
                    v = fmaf(w5,  xsrc[1][r], v);
                    v = fmaf(w6,  xsrc[2][r], v);
                    v = fmaf(w7,  xsrc[3][r], v);
                    float hh = fmaxf(v, 0.f);
                    #pragma unroll
                    for (int cc=0;cc<4;cc++)
                        zz[cc][r] = fmaf(wt[72+cc*8+j], hh, zz[cc][r]);
                }
            }
            #pragma unroll
            for (int cc=0;cc<4;cc++)
                #pragma unroll
                for (int r=0;r<4;r++) z[sub][cc][r] = zz[cc][r];
        }

        // online softmax over this 32-p round (rows live across the 16 lanes of a quad)
        #pragma unroll
        for (int h=0;h<4;h++){
            unsigned short* Pp = Pb_lds + ((wv*4+h)*16 + quad*4)*72 + lrow;
            #pragma unroll
            for (int r=0;r<4;r++){
                float rm = fmaxf(z[0][h][r], z[1][h][r]);
                rm = redmax16(rm);
                float mn = fmaxf(m[h][r], rm);
                float al = __expf(m[h][r] - mn);
                m[h][r] = mn;
                float e0 = __expf(z[0][h][r] - mn);
                float e1 = __expf(z[1][h][r] - mn);
                Pp[r*72]      = bftrunc(e0);
                Pp[r*72 + 16] = bftrunc(e1);
                float rs = redsum16(e0 + e1);
                l[h][r] = l[h][r]*al + rs;
                o[h][0][r] *= al;
                o[h][1][r] *= al;
            }
        }

        // PV: P via wave-private LDS transpose (same-wave lgkm ordering, no barrier)
        #pragma unroll
        for (int h=0;h<4;h++){
            const bf16x8 pf = *(const bf16x8*)(Pb_lds + ((wv*4+h)*16 + lrow)*72 + quad*8);
            const bf16x8 v0 = *(const bf16x8*)(Vt + (b*128 + h*32 + lrow)*2048 + prnd + quad*8);
            const bf16x8 v1 = *(const bf16x8*)(Vt + (b*128 + h*32 + 16 + lrow)*2048 + prnd + quad*8);
            o[h][0] = __builtin_amdgcn_mfma_f32_16x16x32_bf16(pf, v0, o[h][0], 0, 0, 0);
            o[h][1] = __builtin_amdgcn_mfma_f32_16x16x32_bf16(pf, v1, o[h][1], 0, 0, 0);
        }
    }

    // write per-head un-normalized partials
    float* P = part + ((b*128 + qt)*NSLICE + s)*PART_SET;
    #pragma unroll
    for (int h=0;h<4;h++){
        if (lrow == 0){
            float4 mv; mv.x=m[h][0]; mv.y=m[h][1]; mv.z=m[h][2]; mv.w=m[h][3];
            float4 lv; lv.x=l[h][0]; lv.y=l[h][1]; lv.z=l[h][2]; lv.w=l[h][3];
            *(float4*)(P + h*PART_HEAD + quad*4) = mv;
            *(float4*)(P + h*PART_HEAD + 16 + quad*4) = lv;
        }
        #pragma unroll
        for (int r=0;r<4;r++){
            P[h*PART_HEAD + 32 + (quad*4+r)*32 + lrow]      = o[h][0][r];
            P[h*PART_HEAD + 32 + (quad*4+r)*32 + 16 + lrow] = o[h][1][r];
        }
    }
}

// ---------------- kernel 2b: src write-through copy fused into attn was removed;
// do it as part of attn's src read would need out ptr — separate copy kernel instead.
// To avoid a second HBM read of src we do the copy with dwordx4 both ways; src is
// L3-resident so the re-read is cheap (L3 BW >> HBM).
__global__ __launch_bounds__(256) void copy_kernel(
    const float* __restrict__ src, float* __restrict__ dst)
{
    const long i = ((long)blockIdx.x * 256 + threadIdx.x) * 4;
    float4 v = *(const float4*)(src + i);
    *(float4*)(dst + i) = v;
}

// ---------------- kernel 3: slice combine + output projection ----------------
// grid (128, 2), block 256
__global__ __launch_bounds__(256) void combine_kernel(
    const float* __restrict__ part,
    const float* __restrict__ Wout,
    float* __restrict__ out)
{
    __shared__ __align__(16) float O_lds[64*36];
    const int t = threadIdx.x;
    const int qt = blockIdx.x, b = blockIdx.y;

    {
        const int c  = t >> 6;
        const int q  = (t >> 2) & 15;
        const int v0 = (t & 3) * 8;
        const float* base = part + (long)((b*128 + qt)*NSLICE)*PART_SET + c*PART_HEAD;
        float ms[NSLICE];
        float M = -1e30f;
        #pragma unroll
        for (int sl=0; sl<NSLICE; sl++){
            ms[sl] = base[sl*PART_SET + q];
            M = fmaxf(M, ms[sl]);
        }
        float L = 0.f;
        float wsl[NSLICE];
        #pragma unroll
        for (int sl=0; sl<NSLICE; sl++){
            wsl[sl] = __expf(ms[sl] - M);
            L = fmaf(base[sl*PART_SET + 16 + q], wsl[sl], L);
        }
        float acc[8];
        #pragma unroll
        for (int i=0;i<8;i++) acc[i]=0.f;
        #pragma unroll
        for (int sl=0; sl<NSLICE; sl++){
            const float* Op = base + sl*PART_SET + 32 + q*32 + v0;
            float4 a = *(const float4*)(Op);
            float4 bb = *(const float4*)(Op + 4);
            float w = wsl[sl];
            acc[0]=fmaf(a.x,w,acc[0]); acc[1]=fmaf(a.y,w,acc[1]);
            acc[2]=fmaf(a.z,w,acc[2]); acc[3]=fmaf(a.w,w,acc[3]);
            acc[4]=fmaf(bb.x,w,acc[4]); acc[5]=fmaf(bb.y,w,acc[5]);
            acc[6]=fmaf(bb.z,w,acc[6]); acc[7]=fmaf(bb.w,w,acc[7]);
        }
        float invL = 1.f / L;
        float* dst = O_lds + (c*16 + q)*36 + v0;
        float4 oA; oA.x=acc[0]*invL; oA.y=acc[1]*invL; oA.z=acc[2]*invL; oA.w=acc[3]*invL;
        float4 oB; oB.x=acc[4]*invL; oB.y=acc[5]*invL; oB.z=acc[6]*invL; oB.w=acc[7]*invL;
        *(float4*)dst = oA;
        *(float4*)(dst+4) = oB;
    }
    __syncthreads();

    {
        const int mq = t >> 4;
        const int e0 = (t & 15) * 8;
        float acc[8];
        #pragma unroll
        for (int i=0;i<8;i++) acc[i]=0.f;
        #pragma unroll
        for (int cc=0; cc<4; cc++){
            const float* OhRow = O_lds + (cc*16 + mq)*36;
            const float* Wrow = Wout + cc*32*128 + e0;
            #pragma unroll 4
            for (int v=0; v<32; v++){
                float ov = OhRow[v];
                float4 wA = *(const float4*)(Wrow + v*128);
                float4 wB = *(const float4*)(Wrow + v*128 + 4);
                acc[0]=fmaf(ov,wA.x,acc[0]); acc[1]=fmaf(ov,wA.y,acc[1]);
                acc[2]=fmaf(ov,wA.z,acc[2]); acc[3]=fmaf(ov,wA.w,acc[3]);
                acc[4]=fmaf(ov,wB.x,acc[4]); acc[5]=fmaf(ov,wB.y,acc[5]);
                acc[6]=fmaf(ov,wB.z,acc[6]); acc[7]=fmaf(ov,wB.w,acc[7]);
            }
        }
        float* op = out + (b*2048 + qt*16 + mq)*128 + e0;
        float4 oA; oA.x=acc[0]; oA.y=acc[1]; oA.z=acc[2]; oA.w=acc[3];
        float4 oB; oB.x=acc[4]; oB.y=acc[5]; oB.z=acc[6]; oB.w=acc[7];
        *(float4*)op = oA;
        *(float4*)(op+4) = oB;
    }
}

extern "C" void kernel_launch(void* const* d_in, const int* in_sizes, int n_in,
                              void* d_out, int out_size, void* d_ws, size_t ws_size,
                              hipStream_t stream) {
    const float* h    = (const float*)d_in[0];
    const float* src  = (const float*)d_in[1];
    const float* Wq   = (const float*)d_in[2];
    const float* Wk   = (const float*)d_in[3];
    const float* Wv   = (const float*)d_in[4];
    const float* Wout = (const float*)d_in[5];
    const float* w1   = (const float*)d_in[6];
    const float* b1   = (const float*)d_in[7];
    const float* w2   = (const float*)d_in[8];
    const float* b2   = (const float*)d_in[9];
    float* out = (float*)d_out;

    unsigned short* Qb = (unsigned short*)d_ws;       // 1 MB
    unsigned short* Kb = Qb + 524288;                 // 1 MB
    unsigned short* Vt = Kb + 524288;                 // 1 MB (transposed V)
    float* part = (float*)((char*)d_ws + 3*1048576);  // 2048 sets * 2176 f32 = 17.8 MB

    qkv_kernel<<<dim3(128,12), 256, 0, stream>>>(h, Wq, Wk, Wv, Qb, Kb, Vt);
    attn_kernel<<<dim3(32,2,NSLICE), 256, 0, stream>>>(src, Qb, Kb, Vt, w1, b1, w2, b2, part);
    // out[1] = verbatim copy of out_source_attn (4*B*G*G floats = 33.5M)
    copy_kernel<<<dim3(33554432/1024), 256, 0, stream>>>(src, out + OUT0);
    combine_kernel<<<dim3(128,2), 256, 0, stream>>>(part, Wout, out);
}